// Round 13
// baseline (742.184 us; speedup 1.0000x reference)
//
#include <hip/hip_runtime.h>
#include <hip/hip_bf16.h>

#define N_      100000
#define E_      1600000
#define G_      512
#define H_      128
#define T_      10
#define BN_EPS  1e-5f
#define SP_     16         // stats partial buffers (spread atomic contention)

#define NB_     782        // dst buckets of 128 nodes: ceil(100000/128)
#define NBLK_   256        // edge-chunk blocks (6250 edges each)
#define ECHUNK_ 6250
#define SCANN_  (NB_ * NBLK_)             // 200192 bucket-histogram entries
#define SCANB_  ((SCANN_ + 1023) / 1024)  // 196 scan chunks (<=256)
#define POOLB_  512                        // bn_relu_pool pool-role blocks

typedef __attribute__((ext_vector_type(8))) short short8;
typedef __attribute__((ext_vector_type(4))) float floatx4;

__device__ __forceinline__ float bf2f(short s) {
    return __uint_as_float(((unsigned int)(unsigned short)s) << 16);
}
__device__ __forceinline__ short f2bf(float f) {
    unsigned int u = __float_as_uint(f);
    u += 0x7fffu + ((u >> 16) & 1u);          // round-to-nearest-even
    return (short)(u >> 16);
}

// ---------------------------------------------------------------------------
// convert_W: Wt[mat][n*128+k] = bf16(W[mat][k*128+n]); mats 0-3 Wa, 4-7 Wb.
// ---------------------------------------------------------------------------
__global__ __launch_bounds__(256) void convert_W(
    const float* __restrict__ Wa, const float* __restrict__ Wb,
    short* __restrict__ Wt)
{
    int i = blockIdx.x * 256 + threadIdx.x;
    if (i >= 8 * 16384) return;
    int mat = i >> 14;
    int rem = i & 16383;
    int n = rem >> 7;
    int k = rem & 127;
    const float* W = (mat < 4) ? (Wa + (size_t)mat * 16384)
                               : (Wb + (size_t)(mat - 4) * 16384);
    Wt[(size_t)mat * 16384 + n * 128 + k] = f2bf(W[k * 128 + n]);
}

// ---------------------------------------------------------------------------
// side roles (piggybacked on layer-0 kernels; LDS passed in, 512 threads)
// ---------------------------------------------------------------------------
__device__ void side_hist(int* hist, const int* __restrict__ edst,
                          int* __restrict__ BH, int blk)
{
    const int t = threadIdx.x;
    for (int i = t; i < NB_; i += 512) hist[i] = 0;
    __syncthreads();
    const int base = blk * ECHUNK_;
    for (int i = base + t; i < base + ECHUNK_; i += 512)
        atomicAdd(&hist[edst[i] >> 7], 1);
    __syncthreads();
    for (int b = t; b < NB_; b += 512)
        BH[b * NBLK_ + blk] = hist[b];
}

// 512-thread scan of one 1024-element chunk of BH -> BHs; chunk sum -> bsum
__device__ void side_scan(int* sd, const int* __restrict__ X,
                          int* __restrict__ Y, int* __restrict__ bsum, int blk)
{
    const int t = threadIdx.x;
    const int base = blk * 1024 + t * 2;
    int c0 = (base + 0 < SCANN_) ? X[base + 0] : 0;
    int c1 = (base + 1 < SCANN_) ? X[base + 1] : 0;
    int s = c0 + c1;
    sd[t] = s;
    __syncthreads();
    for (int d = 1; d < 512; d <<= 1) {
        int v = (t >= d) ? sd[t - d] : 0;
        __syncthreads();
        sd[t] += v;
        __syncthreads();
    }
    int p = sd[t] - s;
    if (base + 0 < SCANN_) Y[base + 0] = p;
    if (base + 1 < SCANN_) Y[base + 1] = p + c0;
    if (t == 511) bsum[blk] = sd[511];
}

// inline exclusive scan of raw bsum (SCANB_ entries) into bexcl[256] (256 thr)
__device__ __forceinline__ void scan_bsum(const int* __restrict__ bsum,
                                          int* bexcl)
{
    int t = threadIdx.x;
    int v = (t < SCANB_) ? bsum[t] : 0;
    bexcl[t] = v;
    __syncthreads();
    for (int d = 1; d < 256; d <<= 1) {
        int u = (t >= d) ? bexcl[t - d] : 0;
        __syncthreads();
        bexcl[t] += u;
        __syncthreads();
    }
    int inc = bexcl[t];
    __syncthreads();
    bexcl[t] = inc - v;
    __syncthreads();
}

// ---------------------------------------------------------------------------
// fill_buckets: bucket b -> exact CSR eidx + off[] (256 threads).
// ---------------------------------------------------------------------------
__global__ __launch_bounds__(256) void fill_buckets(
    const int* __restrict__ ebuf, const int* __restrict__ BHs,
    const int* __restrict__ bsum, int* __restrict__ eidx,
    int* __restrict__ off)
{
    __shared__ int cnt[128];
    __shared__ int sc[256];
    __shared__ int bexcl[256];
    const int b = blockIdx.x, t = threadIdx.x;
    scan_bsum(bsum, bexcl);
    const int bstart = BHs[b * NBLK_] + bexcl[b >> 2];
    int bend = E_;
    if (b != NB_ - 1)
        bend = BHs[(b + 1) * NBLK_] + bexcl[(b + 1) >> 2];

    if (t < 128) cnt[t] = 0;
    __syncthreads();
    for (int i = bstart + t; i < bend; i += 256)
        atomicAdd(&cnt[(ebuf[i] >> 17) & 127], 1);
    __syncthreads();
    int v = (t < 128) ? cnt[t] : 0;
    sc[t] = v;
    __syncthreads();
    for (int d = 1; d < 128; d <<= 1) {
        int u = (t >= d) ? sc[t - d] : 0;
        __syncthreads();
        sc[t] += u;
        __syncthreads();
    }
    if (t < 128) {
        int node = (b << 7) + t;
        int pfx = sc[t] - v;
        if (node <= N_) off[node] = bstart + pfx;
        cnt[t] = bstart + pfx;                    // cursor
    }
    __syncthreads();
    for (int i = bstart + t; i < bend; i += 256) {
        int e = ebuf[i];
        int pos = atomicAdd(&cnt[(e >> 17) & 127], 1);
        eidx[pos] = e & 0x1FFFF;
    }
}

// ---------------------------------------------------------------------------
// gemm_mfma: 128-row tile, 512 threads = 8 light waves x 16 rows.
// C = act(A) @ W + bias, fused BN-stats into SP_ partial buffers.
// mode 0: A bf16. mode 1: +BN(statsIn)+ReLU fused. mode 2: A fp32.
// Blocks >= gemmBlocks run a side role: 1 = edge hist, 2 = BH scan.
// ---------------------------------------------------------------------------
__global__ __launch_bounds__(512, 6) void gemm_mfma(
    const void* __restrict__ Ain, const short* __restrict__ Wt,
    const float* __restrict__ bias, short* __restrict__ Cout,
    float* __restrict__ statsOut,
    const float* __restrict__ statsIn, const float* __restrict__ gamma,
    const float* __restrict__ beta, int mode, int nrows,
    const int* __restrict__ sideIn, int* __restrict__ sideOut,
    int* __restrict__ sideOut2, int sideMode, int gemmBlocks)
{
    __shared__ __align__(16) short Bs[128][136];
    __shared__ float scale_s[128];
    __shared__ float shift_s[128];

    const int tid = threadIdx.x;

    if ((int)blockIdx.x >= gemmBlocks) {          // side-role block
        int sb = blockIdx.x - gemmBlocks;
        if (sideMode == 1)      side_hist((int*)&Bs[0][0], sideIn, sideOut, sb);
        else if (sideMode == 2) side_scan((int*)&Bs[0][0], sideIn, sideOut, sideOut2, sb);
        return;
    }

    {   // stage W^T: 512 threads x 32 shorts
        int r = tid >> 2;
        int part = (tid & 3) << 5;
        const short* g = Wt + r * 128 + part;
        short* d = &Bs[r][part];
#pragma unroll
        for (int i = 0; i < 4; ++i)
            *(short8*)(d + i * 8) = *(const short8*)(g + i * 8);
    }
    if (mode == 1 && tid < 128) {
        float s1 = 0.f, s2 = 0.f;
#pragma unroll
        for (int p = 0; p < SP_; ++p) {
            s1 += statsIn[p * 256 + tid];
            s2 += statsIn[p * 256 + 128 + tid];
        }
        const float nInv = 1.0f / (float)N_;
        float mu = s1 * nInv;
        float var = s2 * nInv - mu * mu;
        float sc = gamma[tid] * rsqrtf(var + BN_EPS);
        scale_s[tid] = sc;
        shift_s[tid] = beta[tid] - mu * sc;
    }
    __syncthreads();

    const int wave = tid >> 6;
    const int lane = tid & 63;
    const int m = lane & 15;
    const int quad = lane >> 4;
    const int rowBase = blockIdx.x * 128;
    const int row = rowBase + wave * 16 + m;
    const int arow = row < nrows ? row : nrows - 1;

    floatx4 acc[8];
#pragma unroll
    for (int i = 0; i < 8; ++i) acc[i] = (floatx4)0.f;

#pragma unroll
    for (int k0 = 0; k0 < 128; k0 += 32) {
        const int kb = k0 + quad * 8;
        short8 af;
        if (mode == 2) {
            const float* Af = (const float*)Ain + (size_t)arow * 128 + kb;
            float4 x0 = *(const float4*)(Af);
            float4 x1 = *(const float4*)(Af + 4);
            af[0] = f2bf(x0.x); af[1] = f2bf(x0.y);
            af[2] = f2bf(x0.z); af[3] = f2bf(x0.w);
            af[4] = f2bf(x1.x); af[5] = f2bf(x1.y);
            af[6] = f2bf(x1.z); af[7] = f2bf(x1.w);
        } else {
            af = *(const short8*)((const short*)Ain + (size_t)arow * 128 + kb);
            if (mode == 1) {
                float4 sc0 = *(const float4*)&scale_s[kb];
                float4 sc1 = *(const float4*)&scale_s[kb + 4];
                float4 sh0 = *(const float4*)&shift_s[kb];
                float4 sh1 = *(const float4*)&shift_s[kb + 4];
                af[0] = f2bf(fmaxf(fmaf(bf2f(af[0]), sc0.x, sh0.x), 0.f));
                af[1] = f2bf(fmaxf(fmaf(bf2f(af[1]), sc0.y, sh0.y), 0.f));
                af[2] = f2bf(fmaxf(fmaf(bf2f(af[2]), sc0.z, sh0.z), 0.f));
                af[3] = f2bf(fmaxf(fmaf(bf2f(af[3]), sc0.w, sh0.w), 0.f));
                af[4] = f2bf(fmaxf(fmaf(bf2f(af[4]), sc1.x, sh1.x), 0.f));
                af[5] = f2bf(fmaxf(fmaf(bf2f(af[5]), sc1.y, sh1.y), 0.f));
                af[6] = f2bf(fmaxf(fmaf(bf2f(af[6]), sc1.z, sh1.z), 0.f));
                af[7] = f2bf(fmaxf(fmaf(bf2f(af[7]), sc1.w, sh1.w), 0.f));
            }
        }
#pragma unroll
        for (int nt = 0; nt < 8; ++nt) {
            short8 bf = *(const short8*)&Bs[nt * 16 + m][kb];
            acc[nt] = __builtin_amdgcn_mfma_f32_16x16x32_bf16(af, bf, acc[nt], 0, 0, 0);
        }
    }

    float bv[8];
#pragma unroll
    for (int nt = 0; nt < 8; ++nt) bv[nt] = bias[nt * 16 + m];

    float (*Cs)[132] = (float(*)[132])&Bs[0][0];   // 64 x 132 fp32 = 33792 B
    float S1 = 0.f, S2 = 0.f;
#pragma unroll
    for (int half = 0; half < 2; ++half) {
        __syncthreads();
        if ((wave >> 2) == half) {
            int wl = wave & 3;
#pragma unroll
            for (int nt = 0; nt < 8; ++nt)
#pragma unroll
                for (int r = 0; r < 4; ++r)
                    Cs[wl * 16 + quad * 4 + r][nt * 16 + m] = acc[nt][r] + bv[nt];
        }
        __syncthreads();
        {
            int trow = tid >> 3;                   // 0..63
            int tcg = (tid & 7) << 4;              // 16 cols
            int grow = rowBase + half * 64 + trow;
            if (grow < nrows) {
                short* dst = Cout + (size_t)grow * 128 + tcg;
                short8 o0, o1;
#pragma unroll
                for (int j = 0; j < 8; ++j) {
                    o0[j] = f2bf(Cs[trow][tcg + j]);
                    o1[j] = f2bf(Cs[trow][tcg + 8 + j]);
                }
                *(short8*)dst = o0;
                *(short8*)(dst + 8) = o1;
            }
        }
        if (tid < 128) {
            int nvalid = nrows - rowBase - half * 64;
            if (nvalid > 64) nvalid = 64;
            for (int r = 0; r < nvalid; ++r) {
                float v = Cs[r][tid];
                S1 += v; S2 += v * v;
            }
        }
    }
    if (tid < 128) {
        float* part = statsOut + ((blockIdx.x & (SP_ - 1)) << 8);
        atomicAdd(&part[tid], S1);
        atomicAdd(&part[128 + tid], S2);
    }
}

// ---------------------------------------------------------------------------
// bn_relu_pool: 256 threads. Blocks < poolBlocks: BN+ReLU+segment-pool as two
// 128-thread virtual half-blocks (optional h store). Blocks >= poolBlocks:
// scatter_ebuf side role (chunk = blockIdx - poolBlocks).
// ---------------------------------------------------------------------------
__global__ __launch_bounds__(256) void bn_relu_pool(
    const short* __restrict__ Cin, short* __restrict__ hout,
    const float* __restrict__ stats, const float* __restrict__ gamma,
    const float* __restrict__ beta, const int* __restrict__ batch,
    float* __restrict__ pooled, int n,
    const int* __restrict__ esrc, const int* __restrict__ edst,
    const int* __restrict__ BHs, const int* __restrict__ bsum,
    int* __restrict__ ebuf, int poolBlocks)
{
    __shared__ int sbuf[NB_];
    __shared__ int bexcl[256];
    const int tid = threadIdx.x;

    if ((int)blockIdx.x >= poolBlocks) {          // scatter side role
        int blk = blockIdx.x - poolBlocks;
        scan_bsum(bsum, bexcl);
        for (int b = tid; b < NB_; b += 256)
            sbuf[b] = BHs[b * NBLK_ + blk] + bexcl[b >> 2];
        __syncthreads();
        const int base = blk * ECHUNK_;
        for (int i = base + tid; i < base + ECHUNK_; i += 256) {
            int s = esrc[i], d = edst[i];
            int pos = atomicAdd(&sbuf[d >> 7], 1);
            ebuf[pos] = s | ((d & 127) << 17);
        }
        return;
    }

    const int c = tid & 127;
    float s1 = 0.f, s2 = 0.f;
#pragma unroll
    for (int p = 0; p < SP_; ++p) {
        s1 += stats[p * 256 + c];
        s2 += stats[p * 256 + 128 + c];
    }
    const float nInv = 1.0f / (float)N_;
    float mu = s1 * nInv;
    float var = s2 * nInv - mu * mu;
    float sc = gamma[c] * rsqrtf(var + BN_EPS);
    float sh = beta[c] - mu * sc;

    const int nv = poolBlocks * 2;
    const int vblk = blockIdx.x * 2 + (tid >> 7);
    int per = (n + nv - 1) / nv;
    int r0 = vblk * per;
    int r1 = min(n, r0 + per);
    if (r0 >= r1) return;
    int curg = batch[r0];
    float s = 0.f;
    if (hout) {
        for (int r = r0; r < r1; ++r) {
            int g = batch[r];
            if (g != curg) {
                atomicAdd(&pooled[(size_t)curg * 128 + c], s);
                s = 0.f;
                curg = g;
            }
            float v = fmaxf(fmaf(bf2f(Cin[(size_t)r * 128 + c]), sc, sh), 0.f);
            hout[(size_t)r * 128 + c] = f2bf(v);
            s += v;
        }
    } else {
        for (int r = r0; r < r1; ++r) {
            int g = batch[r];
            if (g != curg) {
                atomicAdd(&pooled[(size_t)curg * 128 + c], s);
                s = 0.f;
                curg = g;
            }
            s += fmaxf(fmaf(bf2f(Cin[(size_t)r * 128 + c]), sc, sh), 0.f);
        }
    }
    atomicAdd(&pooled[(size_t)curg * 128 + c], s);
}

// ---------------------------------------------------------------------------
// aggregate: u[i] = (1+eps)*h[i] + sum_{j in N(i)} h[j].
// ---------------------------------------------------------------------------
__global__ __launch_bounds__(256) void aggregate(
    const short* __restrict__ h, short* __restrict__ u,
    const int* __restrict__ off, const int* __restrict__ eidx,
    const float* __restrict__ eps, int li)
{
    int node = blockIdx.x * 4 + (threadIdx.x >> 6);
    if (node >= N_) return;
    int lane = threadIdx.x & 63;
    int col = lane * 2;

    int s0 = off[node];
    int s1 = off[node + 1];
    float se = 1.0f + eps[li];

    ushort2 a = *(const ushort2*)(h + (size_t)node * 128 + col);
    float ax = bf2f((short)a.x) * se;
    float ay = bf2f((short)a.y) * se;

    int j = s0;
    for (; j + 3 < s1; j += 4) {
        int n0 = eidx[j], n1 = eidx[j + 1], n2 = eidx[j + 2], n3 = eidx[j + 3];
        ushort2 v0 = *(const ushort2*)(h + (size_t)n0 * 128 + col);
        ushort2 v1 = *(const ushort2*)(h + (size_t)n1 * 128 + col);
        ushort2 v2 = *(const ushort2*)(h + (size_t)n2 * 128 + col);
        ushort2 v3 = *(const ushort2*)(h + (size_t)n3 * 128 + col);
        ax += (bf2f((short)v0.x) + bf2f((short)v1.x))
            + (bf2f((short)v2.x) + bf2f((short)v3.x));
        ay += (bf2f((short)v0.y) + bf2f((short)v1.y))
            + (bf2f((short)v2.y) + bf2f((short)v3.y));
    }
    for (; j < s1; ++j) {
        int n0 = eidx[j];
        ushort2 v0 = *(const ushort2*)(h + (size_t)n0 * 128 + col);
        ax += bf2f((short)v0.x);
        ay += bf2f((short)v0.y);
    }
    unsigned int o = (unsigned int)(unsigned short)f2bf(ax)
                   | ((unsigned int)(unsigned short)f2bf(ay) << 16);
    __builtin_nontemporal_store(o, (unsigned int*)(u + (size_t)node * 128 + col));
}

// ---------------------------------------------------------------------------
// out_final: inline per-graph count (batch sorted, binary search) + head.
// ---------------------------------------------------------------------------
__global__ void out_final(const float* __restrict__ pooled,
                          const int* __restrict__ batch,
                          const float* __restrict__ Wl,
                          const float* __restrict__ bl, float* __restrict__ out)
{
    int g = blockIdx.x;
    int t = threadIdx.x;
    if (t >= T_) return;
    int lo = 0, hi = N_;
    while (lo < hi) { int mid = (lo + hi) >> 1; if (batch[mid] < g) lo = mid + 1; else hi = mid; }
    int b0 = lo;
    lo = 0; hi = N_;
    while (lo < hi) { int mid = (lo + hi) >> 1; if (batch[mid] < g + 1) lo = mid + 1; else hi = mid; }
    float inv = 1.0f / fmaxf((float)(lo - b0), 1.0f);
    float acc = 0.f;
#pragma unroll
    for (int l = 0; l < 4; ++l) {
        float s = 0.f;
        for (int c = 0; c < 128; ++c)
            s = fmaf(pooled[(size_t)l * (G_ * H_) + g * 128 + c],
                     Wl[(size_t)l * (H_ * T_) + c * T_ + t], s);
        acc += s * inv + bl[l * T_ + t];
    }
    out[g * T_ + t] = 1.0f / (1.0f + expf(-acc));
}

// ---------------------------------------------------------------------------
extern "C" void kernel_launch(void* const* d_in, const int* in_sizes, int n_in,
                              void* d_out, int out_size, void* d_ws, size_t ws_size,
                              hipStream_t stream)
{
    const float* x    = (const float*)d_in[0];
    const int*   ei   = (const int*)d_in[1];
    const int*   batch= (const int*)d_in[2];
    const float* Wa   = (const float*)d_in[3];
    const float* ba   = (const float*)d_in[4];
    const float* ga   = (const float*)d_in[5];
    const float* bea  = (const float*)d_in[6];
    const float* Wb   = (const float*)d_in[7];
    const float* bb   = (const float*)d_in[8];
    const float* gb   = (const float*)d_in[9];
    const float* beb  = (const float*)d_in[10];
    const float* Wl   = (const float*)d_in[11];
    const float* bl   = (const float*)d_in[12];
    const float* eps  = (const float*)d_in[13];
    float* out = (float*)d_out;

    const size_t NH = (size_t)N_ * H_;
    const int statStride = SP_ * 256;          // floats per stats slot
    // workspace layout
    short* A   = (short*)d_ws;                 // N x H bf16 scratch
    short* B   = A + NH;                       // N x H bf16 scratch
    short* C   = B + NH;                       // N x H bf16 (post-BN h)
    short* Wt  = C + NH;                       // 8 x 128 x 128 bf16
    float* stats  = (float*)(Wt + 8 * 16384);  // 8 slots x SP_ x 256  [zeroed]
    float* pooled = stats + 8 * statStride;    // 4 x G x 128          [zeroed]
    int*   BH     = (int*)(pooled + 4 * (size_t)G_ * H_); // SCANN_
    int*   BHs    = BH + SCANN_;               // SCANN_
    int*   bsum   = BHs + SCANN_;              // 256 (raw chunk sums)
    int*   off    = bsum + 256;                // 100352 (>= N_+1)
    int*   ebuf   = off + 100352;              // E (packed src|dstlow)
    int*   eidx   = ebuf + E_;                 // E

    const size_t zbytes = (size_t)(8 * statStride + 4 * G_ * H_) * 4;
    (void)hipMemsetAsync(stats, 0, zbytes, stream);

    const int* esrc = ei;
    const int* edst = ei + E_;

    const int gemmGrid = (N_ + 127) / 128;    // 782 gemm blocks
    const int aggGrid  = (N_ + 3) / 4;

    convert_W<<<512, 256, 0, stream>>>(Wa, Wb, Wt);

    // ---- layer 0 (CSR build piggybacked as extra blocks) ----
    gemm_mfma<<<gemmGrid + NBLK_, 512, 0, stream>>>(
        x, Wt, ba, A, stats, nullptr, nullptr, nullptr, 2, N_,
        edst, BH, nullptr, 1, gemmGrid);                      // + edge hist
    gemm_mfma<<<gemmGrid + SCANB_, 512, 0, stream>>>(
        A, Wt + 4 * 16384, bb, B, stats + statStride,
        stats, ga, bea, 1, N_,
        BH, BHs, bsum, 2, gemmGrid);                          // + BH scan
    bn_relu_pool<<<POOLB_ + NBLK_, 256, 0, stream>>>(
        B, C, stats + statStride, gb, beb, batch, pooled, N_,
        esrc, edst, BHs, bsum, ebuf, POOLB_);                 // + scatter_ebuf
    fill_buckets<<<NB_, 256, 0, stream>>>(ebuf, BHs, bsum, eidx, off);

    // ---- layers 1..3 ----
    for (int l = 1; l < 4; ++l) {
        float* stA = stats + (size_t)(2 * l) * statStride;
        float* stB = stats + (size_t)(2 * l + 1) * statStride;
        aggregate<<<aggGrid, 256, 0, stream>>>(C, A, off, eidx, eps, l - 1);
        gemm_mfma<<<gemmGrid, 512, 0, stream>>>(
            A, Wt + (size_t)l * 16384, ba + l * H_, B, stA,
            nullptr, nullptr, nullptr, 0, N_,
            nullptr, nullptr, nullptr, 0, gemmGrid);
        gemm_mfma<<<gemmGrid, 512, 0, stream>>>(
            B, Wt + (size_t)(4 + l) * 16384, bb + l * H_, A, stB,
            stA, ga + l * H_, bea + l * H_, 1, N_,
            nullptr, nullptr, nullptr, 0, gemmGrid);
        bn_relu_pool<<<POOLB_, 256, 0, stream>>>(
            A, (l < 3) ? C : nullptr, stB, gb + l * H_, beb + l * H_,
            batch, pooled + (size_t)l * G_ * H_, N_,
            nullptr, nullptr, nullptr, nullptr, nullptr, POOLB_);
    }

    out_final<<<G_, 64, 0, stream>>>(pooled, batch, Wl, bl, out);
}

// Round 14
// 628.652 us; speedup vs baseline: 1.1806x; 1.1806x over previous
//
#include <hip/hip_runtime.h>
#include <hip/hip_bf16.h>

#define N_      100000
#define E_      1600000
#define G_      512
#define H_      128
#define T_      10
#define BN_EPS  1e-5f
#define SP_     16         // stats partial buffers (spread atomic contention)

#define NB_     782        // dst buckets of 128 nodes: ceil(100000/128)
#define NBLK_   256        // edge-chunk blocks (6250 edges each)
#define ECHUNK_ 6250
#define SCANN_  (NB_ * NBLK_)             // 200192 bucket-histogram entries
#define SCANB_  ((SCANN_ + 1023) / 1024)  // 196 scan blocks (<=256)

typedef __attribute__((ext_vector_type(8))) short short8;
typedef __attribute__((ext_vector_type(4))) float floatx4;

__device__ __forceinline__ float bf2f(short s) {
    return __uint_as_float(((unsigned int)(unsigned short)s) << 16);
}
__device__ __forceinline__ short f2bf(float f) {
    unsigned int u = __float_as_uint(f);
    u += 0x7fffu + ((u >> 16) & 1u);          // round-to-nearest-even
    return (short)(u >> 16);
}

// ---------------------------------------------------------------------------
// prep: convert weights + per-(bucket, chunk-block) edge histogram.
// ---------------------------------------------------------------------------
__global__ __launch_bounds__(256) void prep(
    const float* __restrict__ Wa, const float* __restrict__ Wb,
    short* __restrict__ Wt, const int* __restrict__ edst,
    int* __restrict__ BH)
{
    __shared__ int hist[NB_];
    const int t = threadIdx.x, blk = blockIdx.x;
    for (int i = t; i < NB_; i += 256) hist[i] = 0;
    __syncthreads();

    for (int i = blk * 256 + t; i < 8 * 16384; i += NBLK_ * 256) {
        int mat = i >> 14;
        int rem = i & 16383;
        int n = rem >> 7;
        int k = rem & 127;
        const float* W = (mat < 4) ? (Wa + (size_t)mat * 16384)
                                   : (Wb + (size_t)(mat - 4) * 16384);
        Wt[(size_t)mat * 16384 + n * 128 + k] = f2bf(W[k * 128 + n]);
    }
    const int base = blk * ECHUNK_;
    for (int i = base + t; i < base + ECHUNK_; i += 256)
        atomicAdd(&hist[edst[i] >> 7], 1);
    __syncthreads();
    for (int b = t; b < NB_; b += 256)
        BH[b * NBLK_ + blk] = hist[b];
}

// ---------------------------------------------------------------------------
// scan1: per-1024-chunk exclusive scan of BH -> BHs; raw block sums -> bsum.
// ---------------------------------------------------------------------------
__global__ __launch_bounds__(256) void scan1(const int* __restrict__ X,
                                             int* __restrict__ Y,
                                             int* __restrict__ bsum, int n)
{
    __shared__ int sd[256];
    int t = threadIdx.x;
    int base = blockIdx.x * 1024 + t * 4;
    int c0 = (base + 0 < n) ? X[base + 0] : 0;
    int c1 = (base + 1 < n) ? X[base + 1] : 0;
    int c2 = (base + 2 < n) ? X[base + 2] : 0;
    int c3 = (base + 3 < n) ? X[base + 3] : 0;
    int s = c0 + c1 + c2 + c3;
    sd[t] = s;
    __syncthreads();
    for (int d = 1; d < 256; d <<= 1) {
        int v = (t >= d) ? sd[t - d] : 0;
        __syncthreads();
        sd[t] += v;
        __syncthreads();
    }
    int p = sd[t] - s;
    if (base + 0 < n) Y[base + 0] = p;
    if (base + 1 < n) Y[base + 1] = p + c0;
    if (base + 2 < n) Y[base + 2] = p + c0 + c1;
    if (base + 3 < n) Y[base + 3] = p + c0 + c1 + c2;
    if (t == 255) bsum[blockIdx.x] = sd[255];
}

// inline exclusive scan of raw bsum (SCANB_ entries) into bexcl[256]
__device__ __forceinline__ void scan_bsum(const int* __restrict__ bsum,
                                          int* bexcl)
{
    int t = threadIdx.x;
    int v = (t < SCANB_) ? bsum[t] : 0;
    bexcl[t] = v;
    __syncthreads();
    for (int d = 1; d < 256; d <<= 1) {
        int u = (t >= d) ? bexcl[t - d] : 0;
        __syncthreads();
        bexcl[t] += u;
        __syncthreads();
    }
    int inc = bexcl[t];
    __syncthreads();
    bexcl[t] = inc - v;
    __syncthreads();
}

// ---------------------------------------------------------------------------
// scatter_ebuf: chunk block -> bucket-grouped ebuf (exclusive regions).
// ebuf entry packed: src (17 bits) | (dst & 127) << 17.
// ---------------------------------------------------------------------------
__global__ __launch_bounds__(256) void scatter_ebuf(
    const int* __restrict__ esrc, const int* __restrict__ edst,
    const int* __restrict__ BHs, const int* __restrict__ bsum,
    int* __restrict__ ebuf)
{
    __shared__ int sbuf[NB_];
    __shared__ int bexcl[256];
    const int t = threadIdx.x, blk = blockIdx.x;
    scan_bsum(bsum, bexcl);
    for (int b = t; b < NB_; b += 256)
        sbuf[b] = BHs[b * NBLK_ + blk] + bexcl[b >> 2];
    __syncthreads();
    const int base = blk * ECHUNK_;
    for (int i = base + t; i < base + ECHUNK_; i += 256) {
        int s = esrc[i], d = edst[i];
        int pos = atomicAdd(&sbuf[d >> 7], 1);
        ebuf[pos] = s | ((d & 127) << 17);
    }
}

// ---------------------------------------------------------------------------
// fill_buckets: bucket b -> exact CSR eidx + off[].
// ---------------------------------------------------------------------------
__global__ __launch_bounds__(256) void fill_buckets(
    const int* __restrict__ ebuf, const int* __restrict__ BHs,
    const int* __restrict__ bsum, int* __restrict__ eidx,
    int* __restrict__ off)
{
    __shared__ int cnt[128];
    __shared__ int sc[256];
    __shared__ int bexcl[256];
    const int b = blockIdx.x, t = threadIdx.x;
    scan_bsum(bsum, bexcl);
    const int bstart = BHs[b * NBLK_] + bexcl[b >> 2];
    int bend = E_;
    if (b != NB_ - 1)
        bend = BHs[(b + 1) * NBLK_] + bexcl[(b + 1) >> 2];

    if (t < 128) cnt[t] = 0;
    __syncthreads();
    for (int i = bstart + t; i < bend; i += 256)
        atomicAdd(&cnt[(ebuf[i] >> 17) & 127], 1);
    __syncthreads();
    int v = (t < 128) ? cnt[t] : 0;
    sc[t] = v;
    __syncthreads();
    for (int d = 1; d < 128; d <<= 1) {
        int u = (t >= d) ? sc[t - d] : 0;
        __syncthreads();
        sc[t] += u;
        __syncthreads();
    }
    if (t < 128) {
        int node = (b << 7) + t;
        int pfx = sc[t] - v;
        if (node <= N_) off[node] = bstart + pfx;
        cnt[t] = bstart + pfx;                    // cursor
    }
    __syncthreads();
    for (int i = bstart + t; i < bend; i += 256) {
        int e = ebuf[i];
        int pos = atomicAdd(&cnt[(e >> 17) & 127], 1);
        eidx[pos] = e & 0x1FFFF;
    }
}

// ---------------------------------------------------------------------------
// gemm_mfma: 128-row tile, 512 threads = 8 light waves x 16 rows each.
// C = act(A) @ W + bias, fused BN-stats into SP_ partial buffers.
// mode 0: A bf16. mode 1: A bf16 + BN(statsIn)+ReLU fused. mode 2: A fp32.
// ---------------------------------------------------------------------------
__global__ __launch_bounds__(512, 6) void gemm_mfma(
    const void* __restrict__ Ain, const short* __restrict__ Wt,
    const float* __restrict__ bias, short* __restrict__ Cout,
    float* __restrict__ statsOut,
    const float* __restrict__ statsIn, const float* __restrict__ gamma,
    const float* __restrict__ beta, int mode, int nrows)
{
    __shared__ __align__(16) short Bs[128][136];
    __shared__ float scale_s[128];
    __shared__ float shift_s[128];

    const int tid = threadIdx.x;

    {   // stage W^T: 512 threads x 32 shorts
        int r = tid >> 2;
        int part = (tid & 3) << 5;
        const short* g = Wt + r * 128 + part;
        short* d = &Bs[r][part];
#pragma unroll
        for (int i = 0; i < 4; ++i)
            *(short8*)(d + i * 8) = *(const short8*)(g + i * 8);
    }
    if (mode == 1 && tid < 128) {
        float s1 = 0.f, s2 = 0.f;
#pragma unroll
        for (int p = 0; p < SP_; ++p) {
            s1 += statsIn[p * 256 + tid];
            s2 += statsIn[p * 256 + 128 + tid];
        }
        const float nInv = 1.0f / (float)N_;
        float mu = s1 * nInv;
        float var = s2 * nInv - mu * mu;
        float sc = gamma[tid] * rsqrtf(var + BN_EPS);
        scale_s[tid] = sc;
        shift_s[tid] = beta[tid] - mu * sc;
    }
    __syncthreads();

    const int wave = tid >> 6;
    const int lane = tid & 63;
    const int m = lane & 15;
    const int quad = lane >> 4;
    const int rowBase = blockIdx.x * 128;
    const int row = rowBase + wave * 16 + m;
    const int arow = row < nrows ? row : nrows - 1;

    floatx4 acc[8];
#pragma unroll
    for (int i = 0; i < 8; ++i) acc[i] = (floatx4)0.f;

#pragma unroll
    for (int k0 = 0; k0 < 128; k0 += 32) {
        const int kb = k0 + quad * 8;
        short8 af;
        if (mode == 2) {
            const float* Af = (const float*)Ain + (size_t)arow * 128 + kb;
            float4 x0 = *(const float4*)(Af);
            float4 x1 = *(const float4*)(Af + 4);
            af[0] = f2bf(x0.x); af[1] = f2bf(x0.y);
            af[2] = f2bf(x0.z); af[3] = f2bf(x0.w);
            af[4] = f2bf(x1.x); af[5] = f2bf(x1.y);
            af[6] = f2bf(x1.z); af[7] = f2bf(x1.w);
        } else {
            af = *(const short8*)((const short*)Ain + (size_t)arow * 128 + kb);
            if (mode == 1) {
                float4 sc0 = *(const float4*)&scale_s[kb];
                float4 sc1 = *(const float4*)&scale_s[kb + 4];
                float4 sh0 = *(const float4*)&shift_s[kb];
                float4 sh1 = *(const float4*)&shift_s[kb + 4];
                af[0] = f2bf(fmaxf(fmaf(bf2f(af[0]), sc0.x, sh0.x), 0.f));
                af[1] = f2bf(fmaxf(fmaf(bf2f(af[1]), sc0.y, sh0.y), 0.f));
                af[2] = f2bf(fmaxf(fmaf(bf2f(af[2]), sc0.z, sh0.z), 0.f));
                af[3] = f2bf(fmaxf(fmaf(bf2f(af[3]), sc0.w, sh0.w), 0.f));
                af[4] = f2bf(fmaxf(fmaf(bf2f(af[4]), sc1.x, sh1.x), 0.f));
                af[5] = f2bf(fmaxf(fmaf(bf2f(af[5]), sc1.y, sh1.y), 0.f));
                af[6] = f2bf(fmaxf(fmaf(bf2f(af[6]), sc1.z, sh1.z), 0.f));
                af[7] = f2bf(fmaxf(fmaf(bf2f(af[7]), sc1.w, sh1.w), 0.f));
            }
        }
#pragma unroll
        for (int nt = 0; nt < 8; ++nt) {
            short8 bf = *(const short8*)&Bs[nt * 16 + m][kb];
            acc[nt] = __builtin_amdgcn_mfma_f32_16x16x32_bf16(af, bf, acc[nt], 0, 0, 0);
        }
    }

    float bv[8];
#pragma unroll
    for (int nt = 0; nt < 8; ++nt) bv[nt] = bias[nt * 16 + m];

    float (*Cs)[132] = (float(*)[132])&Bs[0][0];   // 64 x 132 fp32 = 33792 B
    float S1 = 0.f, S2 = 0.f;
#pragma unroll
    for (int half = 0; half < 2; ++half) {
        __syncthreads();
        if ((wave >> 2) == half) {
            int wl = wave & 3;
#pragma unroll
            for (int nt = 0; nt < 8; ++nt)
#pragma unroll
                for (int r = 0; r < 4; ++r)
                    Cs[wl * 16 + quad * 4 + r][nt * 16 + m] = acc[nt][r] + bv[nt];
        }
        __syncthreads();
        {
            int trow = tid >> 3;                   // 0..63
            int tcg = (tid & 7) << 4;              // 16 cols
            int grow = rowBase + half * 64 + trow;
            if (grow < nrows) {
                short* dst = Cout + (size_t)grow * 128 + tcg;
                short8 o0, o1;
#pragma unroll
                for (int j = 0; j < 8; ++j) {
                    o0[j] = f2bf(Cs[trow][tcg + j]);
                    o1[j] = f2bf(Cs[trow][tcg + 8 + j]);
                }
                *(short8*)dst = o0;
                *(short8*)(dst + 8) = o1;
            }
        }
        if (tid < 128) {
            int nvalid = nrows - rowBase - half * 64;
            if (nvalid > 64) nvalid = 64;
            for (int r = 0; r < nvalid; ++r) {
                float v = Cs[r][tid];
                S1 += v; S2 += v * v;
            }
        }
    }
    if (tid < 128) {
        float* part = statsOut + ((blockIdx.x & (SP_ - 1)) << 8);
        atomicAdd(&part[tid], S1);
        atomicAdd(&part[128 + tid], S2);
    }
}

// ---------------------------------------------------------------------------
// bn_relu_pool v2: BN apply + ReLU + segment pool; optional h store.
// 256 threads = 4 row-segments x (64 lanes x 2 cols); grid 1024 -> 4096
// segments of ~25 rows (4x parallelism vs v1), ushort2 loads, packed store.
// ---------------------------------------------------------------------------
__global__ __launch_bounds__(256) void bn_relu_pool(
    const short* __restrict__ Cin, short* __restrict__ hout,
    const float* __restrict__ stats, const float* __restrict__ gamma,
    const float* __restrict__ beta, const int* __restrict__ batch,
    float* __restrict__ pooled, int n)
{
    const int lane = threadIdx.x & 63;
    const int grp  = threadIdx.x >> 6;        // 0..3
    const int c    = lane << 1;

    float s1a = 0.f, s2a = 0.f, s1b = 0.f, s2b = 0.f;
#pragma unroll
    for (int p = 0; p < SP_; ++p) {
        s1a += stats[p * 256 + c];
        s2a += stats[p * 256 + 128 + c];
        s1b += stats[p * 256 + c + 1];
        s2b += stats[p * 256 + 128 + c + 1];
    }
    const float nInv = 1.0f / (float)N_;
    float mu0 = s1a * nInv, mu1 = s1b * nInv;
    float sc0 = gamma[c] * rsqrtf(s2a * nInv - mu0 * mu0 + BN_EPS);
    float sc1 = gamma[c + 1] * rsqrtf(s2b * nInv - mu1 * mu1 + BN_EPS);
    float sh0 = beta[c] - mu0 * sc0;
    float sh1 = beta[c + 1] - mu1 * sc1;

    const int nseg = gridDim.x * 4;
    const int seg = blockIdx.x * 4 + grp;
    int per = (n + nseg - 1) / nseg;
    int r0 = seg * per;
    int r1 = min(n, r0 + per);
    if (r0 >= r1) return;
    int curg = batch[r0];
    float p0 = 0.f, p1 = 0.f;
    for (int r = r0; r < r1; ++r) {
        int g = batch[r];
        if (g != curg) {
            atomicAdd(&pooled[(size_t)curg * 128 + c], p0);
            atomicAdd(&pooled[(size_t)curg * 128 + c + 1], p1);
            p0 = 0.f; p1 = 0.f; curg = g;
        }
        ushort2 v = *(const ushort2*)(Cin + (size_t)r * 128 + c);
        float h0 = fmaxf(fmaf(bf2f((short)v.x), sc0, sh0), 0.f);
        float h1 = fmaxf(fmaf(bf2f((short)v.y), sc1, sh1), 0.f);
        if (hout) {
            unsigned int o = (unsigned int)(unsigned short)f2bf(h0)
                           | ((unsigned int)(unsigned short)f2bf(h1) << 16);
            *(unsigned int*)(hout + (size_t)r * 128 + c) = o;
        }
        p0 += h0; p1 += h1;
    }
    atomicAdd(&pooled[(size_t)curg * 128 + c], p0);
    atomicAdd(&pooled[(size_t)curg * 128 + c + 1], p1);
}

// ---------------------------------------------------------------------------
// aggregate: u[i] = (1+eps)*h[i] + sum_{j in N(i)} h[j].
// ---------------------------------------------------------------------------
__global__ __launch_bounds__(256) void aggregate(
    const short* __restrict__ h, short* __restrict__ u,
    const int* __restrict__ off, const int* __restrict__ eidx,
    const float* __restrict__ eps, int li)
{
    int node = blockIdx.x * 4 + (threadIdx.x >> 6);
    if (node >= N_) return;
    int lane = threadIdx.x & 63;
    int col = lane * 2;

    int s0 = off[node];
    int s1 = off[node + 1];
    float se = 1.0f + eps[li];

    ushort2 a = *(const ushort2*)(h + (size_t)node * 128 + col);
    float ax = bf2f((short)a.x) * se;
    float ay = bf2f((short)a.y) * se;

    int j = s0;
    for (; j + 3 < s1; j += 4) {
        int n0 = eidx[j], n1 = eidx[j + 1], n2 = eidx[j + 2], n3 = eidx[j + 3];
        ushort2 v0 = *(const ushort2*)(h + (size_t)n0 * 128 + col);
        ushort2 v1 = *(const ushort2*)(h + (size_t)n1 * 128 + col);
        ushort2 v2 = *(const ushort2*)(h + (size_t)n2 * 128 + col);
        ushort2 v3 = *(const ushort2*)(h + (size_t)n3 * 128 + col);
        ax += (bf2f((short)v0.x) + bf2f((short)v1.x))
            + (bf2f((short)v2.x) + bf2f((short)v3.x));
        ay += (bf2f((short)v0.y) + bf2f((short)v1.y))
            + (bf2f((short)v2.y) + bf2f((short)v3.y));
    }
    for (; j < s1; ++j) {
        int n0 = eidx[j];
        ushort2 v0 = *(const ushort2*)(h + (size_t)n0 * 128 + col);
        ax += bf2f((short)v0.x);
        ay += bf2f((short)v0.y);
    }
    unsigned int o = (unsigned int)(unsigned short)f2bf(ax)
                   | ((unsigned int)(unsigned short)f2bf(ay) << 16);
    __builtin_nontemporal_store(o, (unsigned int*)(u + (size_t)node * 128 + col));
}

// ---------------------------------------------------------------------------
// out_final: inline per-graph count (batch sorted, binary search) + head.
// ---------------------------------------------------------------------------
__global__ void out_final(const float* __restrict__ pooled,
                          const int* __restrict__ batch,
                          const float* __restrict__ Wl,
                          const float* __restrict__ bl, float* __restrict__ out)
{
    int g = blockIdx.x;
    int t = threadIdx.x;
    if (t >= T_) return;
    int lo = 0, hi = N_;
    while (lo < hi) { int mid = (lo + hi) >> 1; if (batch[mid] < g) lo = mid + 1; else hi = mid; }
    int b0 = lo;
    lo = 0; hi = N_;
    while (lo < hi) { int mid = (lo + hi) >> 1; if (batch[mid] < g + 1) lo = mid + 1; else hi = mid; }
    float inv = 1.0f / fmaxf((float)(lo - b0), 1.0f);
    float acc = 0.f;
#pragma unroll
    for (int l = 0; l < 4; ++l) {
        float s = 0.f;
        for (int c = 0; c < 128; ++c)
            s = fmaf(pooled[(size_t)l * (G_ * H_) + g * 128 + c],
                     Wl[(size_t)l * (H_ * T_) + c * T_ + t], s);
        acc += s * inv + bl[l * T_ + t];
    }
    out[g * T_ + t] = 1.0f / (1.0f + expf(-acc));
}

// ---------------------------------------------------------------------------
extern "C" void kernel_launch(void* const* d_in, const int* in_sizes, int n_in,
                              void* d_out, int out_size, void* d_ws, size_t ws_size,
                              hipStream_t stream)
{
    const float* x    = (const float*)d_in[0];
    const int*   ei   = (const int*)d_in[1];
    const int*   batch= (const int*)d_in[2];
    const float* Wa   = (const float*)d_in[3];
    const float* ba   = (const float*)d_in[4];
    const float* ga   = (const float*)d_in[5];
    const float* bea  = (const float*)d_in[6];
    const float* Wb   = (const float*)d_in[7];
    const float* bb   = (const float*)d_in[8];
    const float* gb   = (const float*)d_in[9];
    const float* beb  = (const float*)d_in[10];
    const float* Wl   = (const float*)d_in[11];
    const float* bl   = (const float*)d_in[12];
    const float* eps  = (const float*)d_in[13];
    float* out = (float*)d_out;

    const size_t NH = (size_t)N_ * H_;
    const int statStride = SP_ * 256;          // floats per stats slot
    // workspace layout
    short* A   = (short*)d_ws;                 // N x H bf16 scratch
    short* B   = A + NH;                       // N x H bf16 scratch
    short* C   = B + NH;                       // N x H bf16 (post-BN h)
    short* Wt  = C + NH;                       // 8 x 128 x 128 bf16
    float* stats  = (float*)(Wt + 8 * 16384);  // 8 slots x SP_ x 256  [zeroed]
    float* pooled = stats + 8 * statStride;    // 4 x G x 128          [zeroed]
    int*   BH     = (int*)(pooled + 4 * (size_t)G_ * H_); // SCANN_
    int*   BHs    = BH + SCANN_;               // SCANN_
    int*   bsum   = BHs + SCANN_;              // 256 (raw block sums)
    int*   off    = bsum + 256;                // 100352 (>= N_+1)
    int*   ebuf   = off + 100352;              // E (packed src|dstlow)
    int*   eidx   = ebuf + E_;                 // E

    const size_t zbytes = (size_t)(8 * statStride + 4 * G_ * H_) * 4;
    (void)hipMemsetAsync(stats, 0, zbytes, stream);

    const int* esrc = ei;
    const int* edst = ei + E_;

    // ---- setup: weights + CSR (bucket counting sort) ----
    prep<<<NBLK_, 256, 0, stream>>>(Wa, Wb, Wt, edst, BH);
    scan1<<<SCANB_, 256, 0, stream>>>(BH, BHs, bsum, SCANN_);
    scatter_ebuf<<<NBLK_, 256, 0, stream>>>(esrc, edst, BHs, bsum, ebuf);
    fill_buckets<<<NB_, 256, 0, stream>>>(ebuf, BHs, bsum, eidx, off);

    const int gemmGrid = (N_ + 127) / 128;    // 128-row tiles, 512 threads
    const int aggGrid  = (N_ + 3) / 4;

    // ---- layer 0 ----
    gemm_mfma<<<gemmGrid, 512, 0, stream>>>(x, Wt, ba, A, stats,
                                            nullptr, nullptr, nullptr, 2, N_);
    gemm_mfma<<<gemmGrid, 512, 0, stream>>>(A, Wt + 4 * 16384, bb, B,
                                            stats + statStride,
                                            stats, ga, bea, 1, N_);
    bn_relu_pool<<<1024, 256, 0, stream>>>(B, C, stats + statStride, gb, beb,
                                           batch, pooled, N_);

    // ---- layers 1..3 ----
    for (int l = 1; l < 4; ++l) {
        float* stA = stats + (size_t)(2 * l) * statStride;
        float* stB = stats + (size_t)(2 * l + 1) * statStride;
        aggregate<<<aggGrid, 256, 0, stream>>>(C, A, off, eidx, eps, l - 1);
        gemm_mfma<<<gemmGrid, 512, 0, stream>>>(A, Wt + (size_t)l * 16384,
                                                ba + l * H_, B, stA,
                                                nullptr, nullptr, nullptr, 0, N_);
        gemm_mfma<<<gemmGrid, 512, 0, stream>>>(B, Wt + (size_t)(4 + l) * 16384,
                                                bb + l * H_, A, stB,
                                                stA, ga + l * H_, bea + l * H_, 1, N_);
        bn_relu_pool<<<1024, 256, 0, stream>>>(A, (l < 3) ? C : nullptr, stB,
                                               gb + l * H_, beb + l * H_,
                                               batch, pooled + (size_t)l * G_ * H_, N_);
    }

    out_final<<<G_, 64, 0, stream>>>(pooled, batch, Wl, bl, out);
}